// Round 11
// baseline (257.046 us; speedup 1.0000x reference)
//
#include <hip/hip_runtime.h>

#define ALPHA 0.2f

typedef __attribute__((ext_vector_type(8))) short short8;
typedef __attribute__((ext_vector_type(4))) float f32x4;

// ---------- helpers ----------
__device__ __forceinline__ unsigned short f2b(float f) {
  // round-to-nearest-even f32 -> bf16 bits
  unsigned int u; __builtin_memcpy(&u, &f, 4);
  unsigned int r = (u + 0x7FFFu + ((u >> 16) & 1u)) >> 16;
  return (unsigned short)r;
}
__device__ __forceinline__ float b2f(unsigned short v) {
  unsigned int u = ((unsigned int)v) << 16; float f; __builtin_memcpy(&f, &u, 4); return f;
}
__device__ __forceinline__ void gl_lds16(const unsigned short* g, unsigned short* l) {
  // async global->LDS, 16B/lane; LDS dst = wave-uniform base + lane*16
  __builtin_amdgcn_global_load_lds((__attribute__((address_space(1))) void*)g,
                                   (__attribute__((address_space(3))) void*)l, 16, 0, 0);
}
__device__ __forceinline__ uint4 pack8(float4 v0, float4 v1) {
  alignas(16) unsigned short o[8];
  o[0] = f2b(v0.x); o[1] = f2b(v0.y); o[2] = f2b(v0.z); o[3] = f2b(v0.w);
  o[4] = f2b(v1.x); o[5] = f2b(v1.y); o[6] = f2b(v1.z); o[7] = f2b(v1.w);
  return *(const uint4*)o;
}
// counted waits (T4): vmcnt retires in issue order [m135]; vmcnt(6) with the 6
// youngest ops belonging to tile k+2 proves tile k+1 fully landed.
__device__ __forceinline__ void vm6() { asm volatile("s_waitcnt vmcnt(6)" ::: "memory"); }
__device__ __forceinline__ void vm0() { asm volatile("s_waitcnt vmcnt(0)" ::: "memory"); }
__device__ __forceinline__ void lg0() { asm volatile("s_waitcnt lgkmcnt(0)" ::: "memory"); }

// lane-contiguous fp32->bf16: one coalesced float4 load -> coalesced 8B store
__device__ __forceinline__ void cvt_f4(const float* __restrict__ in,
                                       unsigned short* __restrict__ out,
                                       unsigned int f4idx) {
  float4 v = ((const float4*)in)[f4idx];
  alignas(8) unsigned short o[4];
  o[0] = f2b(v.x); o[1] = f2b(v.y); o[2] = f2b(v.z); o[3] = f2b(v.w);
  ((uint2*)out)[f4idx] = *(const uint2*)o;
}

// ---------- prep1: cvt fcw->bf16 + transpose W + zero f1/f2 ----------
__global__ __launch_bounds__(256) void prep1(const float* __restrict__ fcw,
                                             unsigned short* __restrict__ fcwb,
                                             const float* __restrict__ W,
                                             unsigned short* __restrict__ Wt,
                                             float* __restrict__ f1z,
                                             float* __restrict__ f2z) {
  __shared__ alignas(16) unsigned short tile[64][72];
  unsigned int bx = blockIdx.x;
  unsigned int tid = threadIdx.x;
  if (bx < 256u) {
    unsigned int base = bx * 512u;
    cvt_f4(fcw, fcwb, base + tid);
    cvt_f4(fcw, fcwb, base + 256u + tid);
  } else if (bx < 384u) {
    // W transpose: tile (k0..k0+64) x (n0..n0+64)
    unsigned int idx = bx - 256u;                 // 128 blocks: 16 k-tiles x 8 n-tiles
    unsigned int k0 = (idx >> 3) * 64, n0 = (idx & 7) * 64;
    #pragma unroll
    for (int p = 0; p < 4; p++) {
      int r = p * 16 + (tid >> 4);
      int c = (tid & 15) * 4;
      float4 v = *(const float4*)(W + (size_t)(k0 + r) * 512 + n0 + c);
      tile[r][c] = f2b(v.x); tile[r][c + 1] = f2b(v.y);
      tile[r][c + 2] = f2b(v.z); tile[r][c + 3] = f2b(v.w);
    }
    __syncthreads();
    int f = tid >> 2;
    int ic = (tid & 3) * 16;
    alignas(16) unsigned short buf[16];
    #pragma unroll
    for (int k = 0; k < 16; k++) buf[k] = tile[ic + k][f];
    uint4* dst = (uint4*)(Wt + (size_t)(n0 + f) * 1024 + k0 + ic);
    dst[0] = ((const uint4*)buf)[0];
    dst[1] = ((const uint4*)buf)[1];
  } else {
    // zero f1/f2 (16K floats each)
    float4 z = {0.f, 0.f, 0.f, 0.f};
    #pragma unroll
    for (int i = 0; i < 16; i++) ((float4*)f1z)[i * 256 + tid] = z;
    #pragma unroll
    for (int i = 0; i < 16; i++) ((float4*)f2z)[i * 256 + tid] = z;
  }
}

// ---------- rowsum + P in one pass, reading adj DIRECTLY ----------
__global__ __launch_bounds__(256) void rowsum_P(const int* __restrict__ adj,
                                                const float* __restrict__ f1,
                                                const float* __restrict__ f2,
                                                float* __restrict__ invl,
                                                unsigned short* __restrict__ P) {
  int row = blockIdx.x * 4 + (threadIdx.x >> 6);
  int lane = threadIdx.x & 63;
  int b = row >> 10;
  float f1v = f1[row];
  const int4* ap = (const int4*)(adj + (size_t)row * 1024) + lane * 4;
  int4 a0 = ap[0];
  int4 a1 = ap[1];
  int4 a2 = ap[2];
  int4 a3 = ap[3];
  int av[16] = {a0.x, a0.y, a0.z, a0.w, a1.x, a1.y, a1.z, a1.w,
                a2.x, a2.y, a2.z, a2.w, a3.x, a3.y, a3.z, a3.w};
  const float* f2p = f2 + (b << 10) + lane * 16;
  float4 v0 = ((const float4*)f2p)[0];
  float4 v1 = ((const float4*)f2p)[1];
  float4 v2 = ((const float4*)f2p)[2];
  float4 v3 = ((const float4*)f2p)[3];
  float fv[16] = {v0.x, v0.y, v0.z, v0.w, v1.x, v1.y, v1.z, v1.w,
                  v2.x, v2.y, v2.z, v2.w, v3.x, v3.y, v3.z, v3.w};
  float s = 0.f;
  alignas(16) unsigned short o[16];
  #pragma unroll
  for (int j = 0; j < 16; j++) {
    float p = 0.f;
    if (av[j] > 0) {
      float z = f1v + fv[j];
      z = z > 0.f ? z : ALPHA * z;
      p = __expf(z);
      s += p;
    }
    o[j] = f2b(p);
  }
  uint4* dst = (uint4*)(P + (size_t)row * 1024 + lane * 16);
  dst[0] = ((const uint4*)o)[0];
  dst[1] = ((const uint4*)o)[1];
  #pragma unroll
  for (int off = 32; off > 0; off >>= 1) s += __shfl_down(s, off);
  if (lane == 0) invl[row] = 1.0f / s;
}

// ---------- GEMM1 (round-10 proven): C = A_fp32 @ Bt^T + fused epilogues ----
// 128x128 tile, BK=64, 512 threads = 8 waves, each 64x32 (acc[4][2]).
// Double-buffered 64KB LDS -> 2 blocks/CU. 2-phase prefetch loop.
// A fp32 (x), reg-staged cvt issue-early/write-late within one iteration.
// Epilogue: bf16 h at [m][512+n], f1/f2 partials (atomicAdd), ht retile.
__global__ __launch_bounds__(512, 4) void gemm1(
    const float* __restrict__ A_,
    const unsigned short* __restrict__ Bt,
    int K,
    unsigned short* __restrict__ outp, int ldo, int ocol,
    const float* __restrict__ avec,
    unsigned short* __restrict__ htout,
    float* __restrict__ f1g, float* __restrict__ f2g) {
  __shared__ alignas(16) unsigned short smem[32768];        // 64KB
  unsigned short* As = smem;                                 // 2 x 128x64
  unsigned short* Bs = smem + 16384;
  const int tid = threadIdx.x;
  const int lane = tid & 63;
  const int w = tid >> 6;                   // 0..7
  const int m0 = blockIdx.x * 128;
  const int n0 = blockIdx.y * 128;

  f32x4 acc[4][2];
  #pragma unroll
  for (int i = 0; i < 4; i++)
    #pragma unroll
    for (int j = 0; j < 2; j++)
      #pragma unroll
      for (int r = 0; r < 4; r++) acc[i][j][r] = 0.f;

  const int lr = lane >> 3;                 // row within 8-row group
  const int lc = (lane & 7) ^ lr;           // swizzled global col-block
  const float* agf = A_ + (size_t)(m0 + w * 8 + lr) * K + lc * 8;
  const unsigned short* bg = Bt + (size_t)(n0 + w * 8 + lr) * K + lc * 8;
  const int sb0 = (w * 8) * 64;             // t=0 wave LDS base (shorts)
  const int sb1 = (64 + w * 8) * 64;        // t=1
  const int lofs = lane * 8;                // per-lane LDS dst for reg-staged A

  const int wm = (w & 1) * 64;              // 2 m-halves
  const int wn = (w >> 1) * 32;             // 4 n-quarters
  const int row16 = lane & 15;
  const int quad = lane >> 4;
  const int sw = row16 & 7;                 // fragment-read swizzle

  // prologue: stage tile k0=0 into buffer 0
  {
    float4 av[2][2];
    #pragma unroll
    for (int t = 0; t < 2; t++) {
      av[t][0] = *(const float4*)(agf + (size_t)(t * 64) * K);
      av[t][1] = *(const float4*)(agf + (size_t)(t * 64) * K + 4);
    }
    gl_lds16(bg, Bs + sb0);
    gl_lds16(bg + (size_t)64 * K, Bs + sb1);
    *(uint4*)(As + sb0 + lofs) = pack8(av[0][0], av[0][1]);
    *(uint4*)(As + sb1 + lofs) = pack8(av[1][0], av[1][1]);
  }
  __syncthreads();                          // tile 0 visible

  int bufo = 0;
  for (int k0 = 0; k0 < K; k0 += 64) {
    const int nbufo = bufo ^ 8192;
    const bool pf = (k0 + 64 < K);
    float4 av[2][2];
    if (pf) {                               // issue next-tile loads EARLY
      #pragma unroll
      for (int t = 0; t < 2; t++) {
        av[t][0] = *(const float4*)(agf + (k0 + 64) + (size_t)(t * 64) * K);
        av[t][1] = *(const float4*)(agf + (k0 + 64) + (size_t)(t * 64) * K + 4);
      }
      gl_lds16(bg + (k0 + 64), Bs + nbufo + sb0);
      gl_lds16(bg + (k0 + 64) + (size_t)64 * K, Bs + nbufo + sb1);
    }
    short8 af[2][4], bf[2][2];
    #pragma unroll
    for (int s = 0; s < 2; s++) {
      #pragma unroll
      for (int i = 0; i < 4; i++)
        af[s][i] = *(const short8*)(As + bufo + (wm + i * 16 + row16) * 64 + ((s * 4 + quad) ^ sw) * 8);
      #pragma unroll
      for (int j = 0; j < 2; j++)
        bf[s][j] = *(const short8*)(Bs + bufo + (wn + j * 16 + row16) * 64 + ((s * 4 + quad) ^ sw) * 8);
    }
    #pragma unroll
    for (int s = 0; s < 2; s++)
      #pragma unroll
      for (int am = 0; am < 4; am++)
        #pragma unroll
        for (int bn = 0; bn < 2; bn++)
          acc[am][bn] = __builtin_amdgcn_mfma_f32_16x16x32_bf16(af[s][am], bf[s][bn], acc[am][bn], 0, 0, 0);
    if (pf) {                               // write-late: cvt+ds_write after MFMA
      *(uint4*)(As + nbufo + sb0 + lofs) = pack8(av[0][0], av[0][1]);
      *(uint4*)(As + nbufo + sb1 + lofs) = pack8(av[1][0], av[1][1]);
    }
    __syncthreads();
    bufo = nbufo;
  }

  // C/D layout: col = lane&15, row = (lane>>4)*4 + reg  [m89/m91-verified]
  const int col = lane & 15;
  const int r0 = quad * 4;
  #pragma unroll
  for (int am = 0; am < 4; am++)
    #pragma unroll
    for (int bn = 0; bn < 2; bn++)
      #pragma unroll
      for (int r = 0; r < 4; r++) {
        int m = m0 + wm + am * 16 + r0 + r;
        int n = n0 + wn + bn * 16 + col;
        outp[(size_t)m * ldo + ocol + n] = f2b(acc[am][bn][r]);
      }

  // ---- f1/f2 partials from bf16-rounded h (validated R9/R10) ----
  float* fbuf = (float*)smem;               // 256 floats
  if (tid < 256) fbuf[tid] = 0.f;
  __syncthreads();
  float a1v[2], a2v[2];
  #pragma unroll
  for (int bn = 0; bn < 2; bn++) {
    int n = n0 + wn + bn * 16 + col;
    a1v[bn] = avec[n];
    a2v[bn] = avec[512 + n];
  }
  float p1[16], p2[16];
  #pragma unroll
  for (int am = 0; am < 4; am++)
    #pragma unroll
    for (int r = 0; r < 4; r++) {
      float s1 = 0.f, s2 = 0.f;
      #pragma unroll
      for (int bn = 0; bn < 2; bn++) {
        float hb = b2f(f2b(acc[am][bn][r]));
        s1 += hb * a1v[bn];
        s2 += hb * a2v[bn];
      }
      p1[am * 4 + r] = s1;
      p2[am * 4 + r] = s2;
    }
  #pragma unroll
  for (int mask = 1; mask < 16; mask <<= 1)
    #pragma unroll
    for (int e = 0; e < 16; e++) {
      p1[e] += __shfl_xor(p1[e], mask);
      p2[e] += __shfl_xor(p2[e], mask);
    }
  if ((lane & 15) == 0) {
    #pragma unroll
    for (int am = 0; am < 4; am++)
      #pragma unroll
      for (int r = 0; r < 4; r++) {
        int ml = wm + am * 16 + r0 + r;
        atomicAdd(&fbuf[ml], p1[am * 4 + r]);
        atomicAdd(&fbuf[128 + ml], p2[am * 4 + r]);
      }
  }
  __syncthreads();
  if (tid < 128) atomicAdd(&f1g[m0 + tid], fbuf[tid]);
  else if (tid < 256) atomicAdd(&f2g[m0 + tid - 128], fbuf[tid]);
  __syncthreads();

  // ---- ht[b][f][i] = C^T via LDS retile ([128 n][136 stride], 35KB) ----
  #pragma unroll
  for (int am = 0; am < 4; am++)
    #pragma unroll
    for (int bn = 0; bn < 2; bn++)
      #pragma unroll
      for (int r = 0; r < 4; r++) {
        int nloc = wn + bn * 16 + col;
        int mloc = wm + am * 16 + r0 + r;
        smem[nloc * 136 + mloc] = f2b(acc[am][bn][r]);
      }
  __syncthreads();
  const int b = m0 >> 10;
  const int i0 = m0 & 1023;
  #pragma unroll
  for (int p = 0; p < 4; p++) {
    int fr = p * 32 + (tid >> 4);           // [0,128)
    int ib = (tid & 15) * 8;                // [0,128)
    uint4 v = *(const uint4*)(smem + fr * 136 + ib);
    *(uint4*)(htout + ((size_t)(b * 512 + n0 + fr) << 10) + i0 + ib) = v;
  }
}

// ---------- GEMM2/3 (round-6 proven, <=42us): C(MxN) = A @ Bt^T ----------
// BM=128, BN=256, BK=64; 512 threads = 8 waves (2m x 4n), wave tile 64x64
// (acc[4][4], 32 MFMA/wave/K-step). Grid = 256 blocks = 1/CU.
// Per K-tile k: read all 16 frags -> lgkmcnt(0) -> barrier (frees buf[k&1]);
// stage tile k+2 into buf[k&1] (6 gl_lds in flight); setprio(1) 32xMFMA
// setprio(0); vmcnt(6) (k+1 landed, k+2 flying -- never 0 mid-loop); barrier.
// XOR-swizzled LDS: logical (row, colblk cb) at physical cb^(row&7).
// EPI 2: fp32 out, +bias, ELU.   EPI 3: bf16 out, * scale[row].
template <int EPI>
__global__ __launch_bounds__(512, 2) void gemm_bt2(
    const unsigned short* __restrict__ A, size_t aBS,
    const unsigned short* __restrict__ Bt, size_t bBS,
    int K,
    void* __restrict__ outp, size_t oBS, int ldo, int ocol,
    const float* __restrict__ scale,
    const float* __restrict__ bias) {
  __shared__ alignas(16) unsigned short As[2 * 128 * 64];   // 32KB
  __shared__ alignas(16) unsigned short Bs[2 * 256 * 64];   // 64KB
  const int tid = threadIdx.x;
  const int lane = tid & 63;
  const int w = tid >> 6;                   // 0..7
  const int m0 = blockIdx.x * 128;
  const int n0 = blockIdx.y * 256;
  const int zb = blockIdx.z;
  const unsigned short* Ab = A + (size_t)zb * aBS;
  const unsigned short* Btb = Bt + (size_t)zb * bBS;

  f32x4 acc[4][4];
  #pragma unroll
  for (int i = 0; i < 4; i++)
    #pragma unroll
    for (int j = 0; j < 4; j++)
      #pragma unroll
      for (int r = 0; r < 4; r++) acc[i][j][r] = 0.f;

  const int lr = lane >> 3;
  const int lc = (lane & 7) ^ lr;
  const unsigned short* ag = Ab + (size_t)(m0 + w * 8 + lr) * K + lc * 8;
  const unsigned short* bg = Btb + (size_t)(n0 + w * 8 + lr) * K + lc * 8;
  const int asb = w * 8 * 64;               // wave LDS base within A tile
  const int bsb = w * 8 * 64;

  const int wm = (w & 1) * 64;              // 2 m-halves
  const int wn = (w >> 1) * 64;             // 4 n-quarters of 256
  const int row16 = lane & 15;
  const int quad = lane >> 4;
  const int sw = row16 & 7;

  const int nk = K >> 6;

  // ---- prologue: stage tiles 0 (oldest 6) and 1 (youngest 6) ----
  #pragma unroll
  for (int t = 0; t < 2; t++)
    gl_lds16(ag + (size_t)(t * 64) * K, As + t * 4096 + asb);
  #pragma unroll
  for (int t = 0; t < 4; t++)
    gl_lds16(bg + (size_t)(t * 64) * K, Bs + t * 4096 + bsb);
  #pragma unroll
  for (int t = 0; t < 2; t++)
    gl_lds16(ag + 64 + (size_t)(t * 64) * K, As + 8192 + t * 4096 + asb);
  #pragma unroll
  for (int t = 0; t < 4; t++)
    gl_lds16(bg + 64 + (size_t)(t * 64) * K, Bs + 16384 + t * 4096 + bsb);
  vm6();                                    // tile 0 landed; tile 1 in flight
  __builtin_amdgcn_s_barrier();

  for (int k = 0; k < nk; k++) {
    const int ab = (k & 1) * 8192;
    const int bb = (k & 1) * 16384;
    const bool st2 = (k + 2 < nk);
    const bool pub = (k + 1 < nk);

    // read ALL fragments of tile k into registers
    short8 af[2][4], bf[2][4];
    #pragma unroll
    for (int s = 0; s < 2; s++) {
      #pragma unroll
      for (int i = 0; i < 4; i++) {
        af[s][i] = *(const short8*)(As + ab + (wm + i * 16 + row16) * 64 + ((s * 4 + quad) ^ sw) * 8);
        bf[s][i] = *(const short8*)(Bs + bb + (wn + i * 16 + row16) * 64 + ((s * 4 + quad) ^ sw) * 8);
      }
    }
    lg0();                                  // this wave's reads complete
    __builtin_amdgcn_s_barrier();           // ALL waves done reading buf[k&1]

    if (st2) {                              // stage tile k+2 into freed buf[k&1]
      const int ko = (k + 2) * 64;
      #pragma unroll
      for (int t = 0; t < 2; t++)
        gl_lds16(ag + ko + (size_t)(t * 64) * K, As + ab + t * 4096 + asb);
      #pragma unroll
      for (int t = 0; t < 4; t++)
        gl_lds16(bg + ko + (size_t)(t * 64) * K, Bs + bb + t * 4096 + bsb);
    }

    __builtin_amdgcn_s_setprio(1);
    #pragma unroll
    for (int s = 0; s < 2; s++)
      #pragma unroll
      for (int am = 0; am < 4; am++)
        #pragma unroll
        for (int bn = 0; bn < 4; bn++)
          acc[am][bn] = __builtin_amdgcn_mfma_f32_16x16x32_bf16(af[s][am], bf[s][bn], acc[am][bn], 0, 0, 0);
    __builtin_amdgcn_s_setprio(0);

    if (pub) {
      if (st2) vm6(); else vm0();           // tile k+1 fully landed
      __builtin_amdgcn_s_barrier();         // publish buf[(k+1)&1]
    }
  }

  // C/D layout: col = lane&15, row = (lane>>4)*4 + reg
  const int col = lane & 15;
  const int r0 = quad * 4;
  #pragma unroll
  for (int am = 0; am < 4; am++) {
    #pragma unroll
    for (int bn = 0; bn < 4; bn++) {
      #pragma unroll
      for (int r = 0; r < 4; r++) {
        int m = m0 + wm + am * 16 + r0 + r;
        int n = n0 + wn + bn * 16 + col;
        float v = acc[am][bn][r];
        if (EPI == 3) v *= scale[zb * 1024 + m];
        if (EPI == 2) {
          v += bias[n];
          v = v > 0.f ? v : expm1f(v);   // ELU, alpha=1
          ((float*)outp)[(size_t)m * ldo + n] = v;
        } else {
          ((unsigned short*)outp)[(size_t)zb * oBS + (size_t)m * ldo + ocol + n] = f2b(v);
        }
      }
    }
  }
}

// ---------- launch ----------
extern "C" void kernel_launch(void* const* d_in, const int* in_sizes, int n_in,
                              void* d_out, int out_size, void* d_ws, size_t ws_size,
                              hipStream_t stream) {
  const float* x   = (const float*)d_in[0];  // (16,1024,1024)
  const int*   adj = (const int*)d_in[1];    // (16,1024,1024)
  const float* W   = (const float*)d_in[2];  // (1024,512)
  const float* a   = (const float*)d_in[3];  // (1024,1)
  const float* fcw = (const float*)d_in[4];  // (512,1024)  == Bt layout for GEMM3
  const float* fcb = (const float*)d_in[5];  // (512,)
  float* out = (float*)d_out;                // (16,1024,512) fp32
  char* ws = (char*)d_ws;

  // ws layout (~84.2 MiB)
  unsigned short* P    = (unsigned short*)(ws);               // 32MB P~ bf16
  unsigned short* hp   = (unsigned short*)(ws + 33554432);    // 32MB [agg | h] bf16 rows
  unsigned short* ht   = (unsigned short*)(ws + 67108864);    // 16MB h^T per batch
  unsigned short* Wt   = (unsigned short*)(ws + 83886080);    // 1MB
  unsigned short* fcwb = (unsigned short*)(ws + 84934656);    // 1MB
  float* f1            = (float*)(ws + 85983232);             // 64KB
  float* f2            = (float*)(ws + 86048768);             // 64KB
  float* invl          = (float*)(ws + 86114304);             // 64KB

  // 1: tiny prep (fcw cvt + W transpose + zero f1/f2)
  prep1<<<385, 256, 0, stream>>>(fcw, fcwb, W, Wt, f1, f2);

  // 2: GEMM1  h = x @ W -> hp[:,512:1024] + ht + f1/f2 (cvt/transpose/dots fused)
  gemm1<<<dim3(128, 4, 1), 512, 0, stream>>>(x, Wt, 1024, hp, 1024, 512, a, ht, f1, f2);

  // 3: P~ (unnormalized, bf16) + 1/rowsum   (reads adj directly)
  rowsum_P<<<4096, 256, 0, stream>>>(adj, f1, f2, invl, P);

  // 4: GEMM2 (per batch): agg = (P~ @ h) * invl  -> hp[:,0:512]
  gemm_bt2<3><<<dim3(8, 2, 16), 512, 0, stream>>>(P, 1024 * 1024, ht, 512 * 1024, 1024,
                                                  hp, 1024 * 1024, 1024, 0, invl, nullptr);
  // 5: GEMM3: out = elu([agg|h] @ fc_w^T + b)
  gemm_bt2<2><<<dim3(128, 2, 1), 512, 0, stream>>>(hp, 0, fcwb, 0, 1024,
                                                   out, 0, 512, 0, nullptr, fcb);
}

// Round 14
// 255.725 us; speedup vs baseline: 1.0052x; 1.0052x over previous
//
#include <hip/hip_runtime.h>

#define ALPHA 0.2f

typedef __attribute__((ext_vector_type(8))) short short8;
typedef __attribute__((ext_vector_type(4))) float f32x4;

// ---------- helpers ----------
__device__ __forceinline__ unsigned short f2b(float f) {
  // round-to-nearest-even f32 -> bf16 bits
  unsigned int u; __builtin_memcpy(&u, &f, 4);
  unsigned int r = (u + 0x7FFFu + ((u >> 16) & 1u)) >> 16;
  return (unsigned short)r;
}
__device__ __forceinline__ float b2f(unsigned short v) {
  unsigned int u = ((unsigned int)v) << 16; float f; __builtin_memcpy(&f, &u, 4); return f;
}
__device__ __forceinline__ void gl_lds16(const unsigned short* g, unsigned short* l) {
  // async global->LDS, 16B/lane; LDS dst = wave-uniform base + lane*16
  __builtin_amdgcn_global_load_lds((__attribute__((address_space(1))) void*)g,
                                   (__attribute__((address_space(3))) void*)l, 16, 0, 0);
}
__device__ __forceinline__ uint4 pack8(float4 v0, float4 v1) {
  alignas(16) unsigned short o[8];
  o[0] = f2b(v0.x); o[1] = f2b(v0.y); o[2] = f2b(v0.z); o[3] = f2b(v0.w);
  o[4] = f2b(v1.x); o[5] = f2b(v1.y); o[6] = f2b(v1.z); o[7] = f2b(v1.w);
  return *(const uint4*)o;
}

// P~ = mask * exp(lrelu(f1+f2)) for 8 k's; accumulates fp32 rowsum into rs
__device__ __forceinline__ uint4 computeP(int4 a0, int4 a1, float4 fa, float4 fb,
                                          float f1v, float& rs) {
  int av[8] = {a0.x, a0.y, a0.z, a0.w, a1.x, a1.y, a1.z, a1.w};
  float fv[8] = {fa.x, fa.y, fa.z, fa.w, fb.x, fb.y, fb.z, fb.w};
  alignas(16) unsigned short o[8];
  #pragma unroll
  for (int j = 0; j < 8; j++) {
    float p = 0.f;
    if (av[j] > 0) {
      float z = f1v + fv[j];
      z = z > 0.f ? z : ALPHA * z;
      p = __expf(z);
      rs += p;
    }
    o[j] = f2b(p);
  }
  return *(const uint4*)o;
}

// lane-contiguous fp32->bf16: one coalesced float4 load -> coalesced 8B store
__device__ __forceinline__ void cvt_f4(const float* __restrict__ in,
                                       unsigned short* __restrict__ out,
                                       unsigned int f4idx) {
  float4 v = ((const float4*)in)[f4idx];
  alignas(8) unsigned short o[4];
  o[0] = f2b(v.x); o[1] = f2b(v.y); o[2] = f2b(v.z); o[3] = f2b(v.w);
  ((uint2*)out)[f4idx] = *(const uint2*)o;
}

// ---------- prep1: cvt fcw->bf16 + transpose W + zero f1/f2 ----------
__global__ __launch_bounds__(256) void prep1(const float* __restrict__ fcw,
                                             unsigned short* __restrict__ fcwb,
                                             const float* __restrict__ W,
                                             unsigned short* __restrict__ Wt,
                                             float* __restrict__ f1z,
                                             float* __restrict__ f2z) {
  __shared__ alignas(16) unsigned short tile[64][72];
  unsigned int bx = blockIdx.x;
  unsigned int tid = threadIdx.x;
  if (bx < 256u) {
    unsigned int base = bx * 512u;
    cvt_f4(fcw, fcwb, base + tid);
    cvt_f4(fcw, fcwb, base + 256u + tid);
  } else if (bx < 384u) {
    // W transpose: tile (k0..k0+64) x (n0..n0+64)
    unsigned int idx = bx - 256u;                 // 128 blocks: 16 k-tiles x 8 n-tiles
    unsigned int k0 = (idx >> 3) * 64, n0 = (idx & 7) * 64;
    #pragma unroll
    for (int p = 0; p < 4; p++) {
      int r = p * 16 + (tid >> 4);
      int c = (tid & 15) * 4;
      float4 v = *(const float4*)(W + (size_t)(k0 + r) * 512 + n0 + c);
      tile[r][c] = f2b(v.x); tile[r][c + 1] = f2b(v.y);
      tile[r][c + 2] = f2b(v.z); tile[r][c + 3] = f2b(v.w);
    }
    __syncthreads();
    int f = tid >> 2;
    int ic = (tid & 3) * 16;
    alignas(16) unsigned short buf[16];
    #pragma unroll
    for (int k = 0; k < 16; k++) buf[k] = tile[ic + k][f];
    uint4* dst = (uint4*)(Wt + (size_t)(n0 + f) * 1024 + k0 + ic);
    dst[0] = ((const uint4*)buf)[0];
    dst[1] = ((const uint4*)buf)[1];
  } else {
    // zero f1/f2 (16K floats each)
    float4 z = {0.f, 0.f, 0.f, 0.f};
    #pragma unroll
    for (int i = 0; i < 16; i++) ((float4*)f1z)[i * 256 + tid] = z;
    #pragma unroll
    for (int i = 0; i < 16; i++) ((float4*)f2z)[i * 256 + tid] = z;
  }
}

// ---------- bf16 GEMM (R10-proven): C(MxN) = A(MxK) @ Bt(NxK)^T ----------
// 128x128 tile, BK=64, 512 threads = 8 waves, each 64x32 (acc[4][2]).
// Double-buffered 64KB LDS -> 2 blocks/CU. 2-phase prefetch loop.
// CVTA=1 (GEMM1): A fp32 (x), reg-staged cvt issue-early/write-late.
// XOR-swizzled LDS: logical (row, colblk cb) at physical cb^(row&7).
// EPI 1: bf16 out at [m][ocol+n], + f1/f2 partials (atomicAdd; a via `scale`),
//        + ht[b][f][i]=C^T via LDS retile  (validated R9/R10)
// EPI 2: fp32 out, +bias, ELU
template <int EPI, int CVTA>
__global__ __launch_bounds__(512, 4) void gemm_bt(
    const void* __restrict__ A_, size_t aBS,
    const unsigned short* __restrict__ Bt, size_t bBS,
    int K,
    void* __restrict__ outp, size_t oBS, int ldo, int ocol,
    const float* __restrict__ scale,
    const float* __restrict__ bias,
    unsigned short* __restrict__ htout,
    float* __restrict__ f1g, float* __restrict__ f2g) {
  __shared__ alignas(16) unsigned short smem[32768];        // 64KB
  unsigned short* As = smem;                                 // 2 x 128x64
  unsigned short* Bs = smem + 16384;
  const int tid = threadIdx.x;
  const int lane = tid & 63;
  const int w = tid >> 6;                   // 0..7
  const int m0 = blockIdx.x * 128;
  const int n0 = blockIdx.y * 128;
  const int zb = blockIdx.z;
  const unsigned short* Btb = Bt + (size_t)zb * bBS;

  f32x4 acc[4][2];
  #pragma unroll
  for (int i = 0; i < 4; i++)
    #pragma unroll
    for (int j = 0; j < 2; j++)
      #pragma unroll
      for (int r = 0; r < 4; r++) acc[i][j][r] = 0.f;

  const int lr = lane >> 3;                 // row within 8-row group
  const int lc = (lane & 7) ^ lr;           // swizzled global col-block
  const unsigned short* ag = nullptr;
  const float* agf = nullptr;
  if (CVTA)
    agf = (const float*)A_ + (size_t)(m0 + w * 8 + lr) * K + lc * 8;
  else
    ag = (const unsigned short*)A_ + (size_t)zb * aBS + (size_t)(m0 + w * 8 + lr) * K + lc * 8;
  const unsigned short* bg = Btb + (size_t)(n0 + w * 8 + lr) * K + lc * 8;
  const int sb0 = (w * 8) * 64;             // t=0 wave LDS base (shorts)
  const int sb1 = (64 + w * 8) * 64;        // t=1
  const int lofs = lane * 8;                // per-lane LDS dst for reg-staged A

  const int wm = (w & 1) * 64;              // 2 m-halves
  const int wn = (w >> 1) * 32;             // 4 n-quarters
  const int row16 = lane & 15;
  const int quad = lane >> 4;
  const int sw = row16 & 7;                 // fragment-read swizzle

  // prologue: stage tile k0=0 into buffer 0
  if (CVTA) {
    float4 av[2][2];
    #pragma unroll
    for (int t = 0; t < 2; t++) {
      av[t][0] = *(const float4*)(agf + (size_t)(t * 64) * K);
      av[t][1] = *(const float4*)(agf + (size_t)(t * 64) * K + 4);
    }
    gl_lds16(bg, Bs + sb0);
    gl_lds16(bg + (size_t)64 * K, Bs + sb1);
    *(uint4*)(As + sb0 + lofs) = pack8(av[0][0], av[0][1]);
    *(uint4*)(As + sb1 + lofs) = pack8(av[1][0], av[1][1]);
  } else {
    gl_lds16(ag, As + sb0);
    gl_lds16(ag + (size_t)64 * K, As + sb1);
    gl_lds16(bg, Bs + sb0);
    gl_lds16(bg + (size_t)64 * K, Bs + sb1);
  }
  __syncthreads();                          // tile 0 visible

  int bufo = 0;
  for (int k0 = 0; k0 < K; k0 += 64) {
    const int nbufo = bufo ^ 8192;
    const bool pf = (k0 + 64 < K);
    float4 av[2][2];
    if (pf) {                               // issue next-tile loads EARLY
      if (CVTA) {
        #pragma unroll
        for (int t = 0; t < 2; t++) {
          av[t][0] = *(const float4*)(agf + (k0 + 64) + (size_t)(t * 64) * K);
          av[t][1] = *(const float4*)(agf + (k0 + 64) + (size_t)(t * 64) * K + 4);
        }
      } else {
        gl_lds16(ag + (k0 + 64), As + nbufo + sb0);
        gl_lds16(ag + (k0 + 64) + (size_t)64 * K, As + nbufo + sb1);
      }
      gl_lds16(bg + (k0 + 64), Bs + nbufo + sb0);
      gl_lds16(bg + (k0 + 64) + (size_t)64 * K, Bs + nbufo + sb1);
    }
    short8 af[2][4], bf[2][2];
    #pragma unroll
    for (int s = 0; s < 2; s++) {
      #pragma unroll
      for (int i = 0; i < 4; i++)
        af[s][i] = *(const short8*)(As + bufo + (wm + i * 16 + row16) * 64 + ((s * 4 + quad) ^ sw) * 8);
      #pragma unroll
      for (int j = 0; j < 2; j++)
        bf[s][j] = *(const short8*)(Bs + bufo + (wn + j * 16 + row16) * 64 + ((s * 4 + quad) ^ sw) * 8);
    }
    #pragma unroll
    for (int s = 0; s < 2; s++)
      #pragma unroll
      for (int am = 0; am < 4; am++)
        #pragma unroll
        for (int bn = 0; bn < 2; bn++)
          acc[am][bn] = __builtin_amdgcn_mfma_f32_16x16x32_bf16(af[s][am], bf[s][bn], acc[am][bn], 0, 0, 0);
    if (pf && CVTA) {                       // write-late: cvt+ds_write after MFMA
      *(uint4*)(As + nbufo + sb0 + lofs) = pack8(av[0][0], av[0][1]);
      *(uint4*)(As + nbufo + sb1 + lofs) = pack8(av[1][0], av[1][1]);
    }
    __syncthreads();
    bufo = nbufo;
  }

  // C/D layout: col = lane&15, row = (lane>>4)*4 + reg  [m89/m91-verified]
  const int col = lane & 15;
  const int r0 = quad * 4;
  #pragma unroll
  for (int am = 0; am < 4; am++) {
    #pragma unroll
    for (int bn = 0; bn < 2; bn++) {
      #pragma unroll
      for (int r = 0; r < 4; r++) {
        int m = m0 + wm + am * 16 + r0 + r;
        int n = n0 + wn + bn * 16 + col;
        float v = acc[am][bn][r];
        if (EPI == 2) {
          v += bias[n];
          v = v > 0.f ? v : expm1f(v);   // ELU, alpha=1
          ((float*)outp)[(size_t)m * ldo + n] = v;
        } else {
          ((unsigned short*)outp)[(size_t)zb * oBS + (size_t)m * ldo + ocol + n] = f2b(v);
        }
      }
    }
  }

  if (EPI == 1) {
    // ---- f1/f2 partials from bf16-rounded h (validated R9/R10) ----
    float* fbuf = (float*)smem;             // 256 floats
    if (tid < 256) fbuf[tid] = 0.f;
    __syncthreads();
    float a1v[2], a2v[2];
    #pragma unroll
    for (int bn = 0; bn < 2; bn++) {
      int n = n0 + wn + bn * 16 + col;
      a1v[bn] = scale[n];
      a2v[bn] = scale[512 + n];
    }
    float p1[16], p2[16];
    #pragma unroll
    for (int am = 0; am < 4; am++)
      #pragma unroll
      for (int r = 0; r < 4; r++) {
        float s1 = 0.f, s2 = 0.f;
        #pragma unroll
        for (int bn = 0; bn < 2; bn++) {
          float hb = b2f(f2b(acc[am][bn][r]));
          s1 += hb * a1v[bn];
          s2 += hb * a2v[bn];
        }
        p1[am * 4 + r] = s1;
        p2[am * 4 + r] = s2;
      }
    #pragma unroll
    for (int mask = 1; mask < 16; mask <<= 1)
      #pragma unroll
      for (int e = 0; e < 16; e++) {
        p1[e] += __shfl_xor(p1[e], mask);
        p2[e] += __shfl_xor(p2[e], mask);
      }
    if ((lane & 15) == 0) {
      #pragma unroll
      for (int am = 0; am < 4; am++)
        #pragma unroll
        for (int r = 0; r < 4; r++) {
          int ml = wm + am * 16 + r0 + r;
          atomicAdd(&fbuf[ml], p1[am * 4 + r]);
          atomicAdd(&fbuf[128 + ml], p2[am * 4 + r]);
        }
    }
    __syncthreads();
    if (tid < 128) atomicAdd(&f1g[m0 + tid], fbuf[tid]);
    else if (tid < 256) atomicAdd(&f2g[m0 + tid - 128], fbuf[tid]);
    __syncthreads();

    // ---- ht[b][f][i] = C^T via LDS retile ([128 n][136 stride], 35KB) ----
    #pragma unroll
    for (int am = 0; am < 4; am++)
      #pragma unroll
      for (int bn = 0; bn < 2; bn++)
        #pragma unroll
        for (int r = 0; r < 4; r++) {
          int nloc = wn + bn * 16 + col;
          int mloc = wm + am * 16 + r0 + r;
          smem[nloc * 136 + mloc] = f2b(acc[am][bn][r]);
        }
    __syncthreads();
    const int b = m0 >> 10;
    const int i0 = m0 & 1023;
    #pragma unroll
    for (int p = 0; p < 4; p++) {
      int fr = p * 32 + (tid >> 4);         // [0,128)
      int ib = (tid & 15) * 8;              // [0,128)
      uint4 v = *(const uint4*)(smem + fr * 136 + ib);
      *(uint4*)(htout + ((size_t)(b * 512 + n0 + fr) << 10) + i0 + ib) = v;
    }
  }
}

// ---------- GEMM2 fused: agg = softmax-normalized (P~ @ h) without P buffer --
// Same R10 loop geometry (128x128 tile, BK=64, acc[4][2], dbuf 64KB LDS,
// 2 blocks/CU). A-tile = P~ computed ON THE FLY in staging: issue adj(int4x2)
// + f2(float4x2) loads early (with B gl_lds), after MFMA compute
// mask*exp(lrelu(f1+f2)) -> pack bf16 -> ds_write (CVTA pattern, proven).
// Rowsum accumulated per-lane across ALL K-steps; 8-lane shfl reduce at end
// -> invl in LDS -> epilogue scales. Deletes rowsum_P kernel + 32MB P buffer.
__global__ __launch_bounds__(512, 4) void gemm2f(
    const int* __restrict__ adj,
    const float* __restrict__ f1,
    const float* __restrict__ f2,
    const unsigned short* __restrict__ ht,
    unsigned short* __restrict__ hp) {
  __shared__ alignas(16) unsigned short smem[32768];        // 64KB
  unsigned short* As = smem;                                 // 2 x 128x64
  unsigned short* Bs = smem + 16384;
  const int K = 1024;
  const int tid = threadIdx.x;
  const int lane = tid & 63;
  const int w = tid >> 6;
  const int m0 = blockIdx.x * 128;
  const int n0 = blockIdx.y * 128;
  const int zb = blockIdx.z;
  const unsigned short* Btb = ht + (size_t)zb * 512 * 1024;

  f32x4 acc[4][2];
  #pragma unroll
  for (int i = 0; i < 4; i++)
    #pragma unroll
    for (int j = 0; j < 2; j++)
      #pragma unroll
      for (int r = 0; r < 4; r++) acc[i][j][r] = 0.f;

  const int lr = lane >> 3;
  const int lc = (lane & 7) ^ lr;
  const int row0 = m0 + w * 8 + lr;         // within-batch row, t=0 (t=1: +64)
  const int* ag0 = adj + (size_t)zb * 1048576 + (size_t)row0 * 1024 + lc * 8;
  const int* ag1 = ag0 + 64 * 1024;
  const float f1v0 = f1[zb * 1024 + row0];
  const float f1v1 = f1[zb * 1024 + row0 + 64];
  const float* f2p = f2 + zb * 1024;        // + k
  const unsigned short* bg = Btb + (size_t)(n0 + w * 8 + lr) * K + lc * 8;
  const int sb0 = (w * 8) * 64;
  const int sb1 = (64 + w * 8) * 64;
  const int lofs = lane * 8;

  const int wm = (w & 1) * 64;
  const int wn = (w >> 1) * 32;
  const int row16 = lane & 15;
  const int quad = lane >> 4;
  const int sw = row16 & 7;

  float rs0 = 0.f, rs1 = 0.f;               // fp32 rowsum partials

  // prologue: stage tile 0
  {
    int4 a00 = ((const int4*)ag0)[0], a01 = ((const int4*)ag0)[1];
    int4 a10 = ((const int4*)ag1)[0], a11 = ((const int4*)ag1)[1];
    float4 fa = *(const float4*)(f2p + lc * 8);
    float4 fb = *(const float4*)(f2p + lc * 8 + 4);
    gl_lds16(bg, Bs + sb0);
    gl_lds16(bg + (size_t)64 * K, Bs + sb1);
    *(uint4*)(As + sb0 + lofs) = computeP(a00, a01, fa, fb, f1v0, rs0);
    *(uint4*)(As + sb1 + lofs) = computeP(a10, a11, fa, fb, f1v1, rs1);
  }
  __syncthreads();

  int bufo = 0;
  for (int k0 = 0; k0 < K; k0 += 64) {
    const int nbufo = bufo ^ 8192;
    const bool pf = (k0 + 64 < K);
    int4 a00, a01, a10, a11;
    float4 fa, fb;
    if (pf) {                               // issue next-tile loads EARLY
      const int ko = k0 + 64;
      a00 = *(const int4*)(ag0 + ko); a01 = *(const int4*)(ag0 + ko + 4);
      a10 = *(const int4*)(ag1 + ko); a11 = *(const int4*)(ag1 + ko + 4);
      fa = *(const float4*)(f2p + ko + lc * 8);
      fb = *(const float4*)(f2p + ko + lc * 8 + 4);
      gl_lds16(bg + ko, Bs + nbufo + sb0);
      gl_lds16(bg + ko + (size_t)64 * K, Bs + nbufo + sb1);
    }
    short8 af[2][4], bf[2][2];
    #pragma unroll
    for (int s = 0; s < 2; s++) {
      #pragma unroll
      for (int i = 0; i < 4; i++)
        af[s][i] = *(const short8*)(As + bufo + (wm + i * 16 + row16) * 64 + ((s * 4 + quad) ^ sw) * 8);
      #pragma unroll
      for (int j = 0; j < 2; j++)
        bf[s][j] = *(const short8*)(Bs + bufo + (wn + j * 16 + row16) * 64 + ((s * 4 + quad) ^ sw) * 8);
    }
    #pragma unroll
    for (int s = 0; s < 2; s++)
      #pragma unroll
      for (int am = 0; am < 4; am++)
        #pragma unroll
        for (int bn = 0; bn < 2; bn++)
          acc[am][bn] = __builtin_amdgcn_mfma_f32_16x16x32_bf16(af[s][am], bf[s][bn], acc[am][bn], 0, 0, 0);
    if (pf) {                               // write-late: P compute + ds_write
      *(uint4*)(As + nbufo + sb0 + lofs) = computeP(a00, a01, fa, fb, f1v0, rs0);
      *(uint4*)(As + nbufo + sb1 + lofs) = computeP(a10, a11, fa, fb, f1v1, rs1);
    }
    __syncthreads();
    bufo = nbufo;
  }

  // rowsum: 8 lanes (same lr group) share a row -> reduce, then invl in LDS
  #pragma unroll
  for (int msk = 1; msk < 8; msk <<= 1) {
    rs0 += __shfl_xor(rs0, msk);
    rs1 += __shfl_xor(rs1, msk);
  }
  float* fbuf = (float*)smem;               // 128 rowsums + 128 invl
  if ((lane & 7) == 0) {
    fbuf[w * 8 + lr] = rs0;
    fbuf[64 + w * 8 + lr] = rs1;
  }
  __syncthreads();
  if (tid < 128) fbuf[128 + tid] = 1.0f / fbuf[tid];
  __syncthreads();

  // epilogue: hp[zb][m][n] = bf16(acc * invl[m])
  const int col = lane & 15;
  const int r0 = quad * 4;
  #pragma unroll
  for (int am = 0; am < 4; am++) {
    #pragma unroll
    for (int bn = 0; bn < 2; bn++) {
      #pragma unroll
      for (int r = 0; r < 4; r++) {
        int ml = wm + am * 16 + r0 + r;
        int m = m0 + ml;
        int n = n0 + wn + bn * 16 + col;
        hp[(size_t)zb * 1048576 + (size_t)m * 1024 + n] =
            f2b(acc[am][bn][r] * fbuf[128 + ml]);
      }
    }
  }
}

// ---------- launch ----------
extern "C" void kernel_launch(void* const* d_in, const int* in_sizes, int n_in,
                              void* d_out, int out_size, void* d_ws, size_t ws_size,
                              hipStream_t stream) {
  const float* x   = (const float*)d_in[0];  // (16,1024,1024)
  const int*   adj = (const int*)d_in[1];    // (16,1024,1024)
  const float* W   = (const float*)d_in[2];  // (1024,512)
  const float* a   = (const float*)d_in[3];  // (1024,1)
  const float* fcw = (const float*)d_in[4];  // (512,1024)  == Bt layout for GEMM3
  const float* fcb = (const float*)d_in[5];  // (512,)
  float* out = (float*)d_out;                // (16,1024,512) fp32
  char* ws = (char*)d_ws;

  // ws layout (P slot unused now; offsets kept)
  unsigned short* hp   = (unsigned short*)(ws + 33554432);    // 32MB [agg | h] bf16 rows
  unsigned short* ht   = (unsigned short*)(ws + 67108864);    // 16MB h^T per batch
  unsigned short* Wt   = (unsigned short*)(ws + 83886080);    // 1MB
  unsigned short* fcwb = (unsigned short*)(ws + 84934656);    // 1MB
  float* f1            = (float*)(ws + 85983232);             // 64KB
  float* f2            = (float*)(ws + 86048768);             // 64KB

  // 1: tiny prep (fcw cvt + W transpose + zero f1/f2)
  prep1<<<385, 256, 0, stream>>>(fcw, fcwb, W, Wt, f1, f2);

  // 2: GEMM1  h = x @ W -> hp[:,512:1024] + ht + f1/f2 (cvt/transpose/dots fused)
  gemm_bt<1, 1><<<dim3(128, 4, 1), 512, 0, stream>>>(x, 0, Wt, 0, 1024,
                                                     hp, 0, 1024, 512, a, nullptr,
                                                     ht, f1, f2);
  // 3: GEMM2 fused: agg = softmax(adj,f1,f2) @ h  -> hp[:,0:512]
  //    (P computed in staging; rowsum/invl in-kernel; rowsum_P deleted)
  gemm2f<<<dim3(8, 4, 16), 512, 0, stream>>>(adj, f1, f2, ht, hp);

  // 4: GEMM3: out = elu([agg|h] @ fc_w^T + b)
  gemm_bt<2, 0><<<dim3(128, 4, 1), 512, 0, stream>>>(hp, 0, fcwb, 0, 1024,
                                                     out, 0, 512, 0, nullptr, fcb,
                                                     nullptr, nullptr, nullptr);
}